// Round 11
// baseline (173.330 us; speedup 1.0000x reference)
//
#include <hip/hip_runtime.h>
#include <hip/hip_bf16.h>

// StandardAttention: B=2, N=4096, D=512, H=8, HD=64, causal.
// R20: combine fused into gemm<1>'s A-staging (5 -> 4 launches, Og 16MB HBM
// round-trip deleted). Works because per-K-step column range [kk,kk+64) is one
// head (hh=kk>>6) and rows of a block share one batch -> bh block-uniform per
// kk; the combine reduce is 4 contiguous 16B slab reads + per-row 1/sum(l)
// scale (precomputed linv[8][128] in LDS). gemm<1> now TN=128, grid (4,64);
// XCD swizzle puts the 4 col-blocks of a row-panel on one XCD so the 4x
// o_part re-read is L2-resident. attn/gemm<0>/prep frozen (R19).

typedef __bf16 bf16_t;
typedef __bf16 bf16x2 __attribute__((ext_vector_type(2)));
typedef __bf16 bf16x4 __attribute__((ext_vector_type(4)));
typedef __bf16 bf16x8 __attribute__((ext_vector_type(8)));
typedef float  f32x4  __attribute__((ext_vector_type(4)));
typedef unsigned int uint32x4 __attribute__((ext_vector_type(4)));

// async global->LDS, 16 B per lane; lds dst must be wave-uniform base (HW puts
// lane i at base + i*16)
__device__ __forceinline__ void gload_lds16(const bf16_t* g, bf16_t* l) {
    __builtin_amdgcn_global_load_lds(
        (const __attribute__((address_space(1))) void*)g,
        (__attribute__((address_space(3))) void*)l, 16, 0, 0);
}

// ---------------- fused prep: x->bf16 convert + both weight transposes ------
// blocks [0,4096): convert x (fp32->bf16, float4/lane)
// blocks [4096,4288): Wqkv [512][1536] -> WqT [1536][512] bf16 (64x64 tiles)
// blocks [4288,4352): Wout [512][512]  -> WoT [512][512]  bf16

__device__ __forceinline__ void transpose_tile_body(
    const float* __restrict__ in, bf16_t* __restrict__ out, int N,
    int n0, int k0, int tid, bf16_t (*T)[72])
{
    #pragma unroll
    for (int pass = 0; pass < 4; ++pass) {
        int kk = pass * 16 + (tid >> 4), nn = (tid & 15) * 4;
        float4 v = *(const float4*)(in + (size_t)(k0 + kk) * N + n0 + nn);
        T[nn + 0][kk] = (bf16_t)v.x; T[nn + 1][kk] = (bf16_t)v.y;
        T[nn + 2][kk] = (bf16_t)v.z; T[nn + 3][kk] = (bf16_t)v.w;
    }
    __syncthreads();
    #pragma unroll
    for (int pass = 0; pass < 2; ++pass) {
        int n = pass * 32 + (tid >> 3), c8 = (tid & 7) * 8;
        *(bf16x8*)(out + (size_t)(n0 + n) * 512 + k0 + c8) = *(const bf16x8*)&T[n][c8];
    }
}

__global__ void prep_kernel(const float* __restrict__ x, bf16_t* __restrict__ xb,
                            const float* __restrict__ Wqkv, bf16_t* __restrict__ WqT,
                            const float* __restrict__ Wout, bf16_t* __restrict__ WoT)
{
    __shared__ bf16_t T[64][72];
    const int bid = blockIdx.x, tid = threadIdx.x;
    if (bid < 4096) {
        int i = bid * 256 + tid;
        float4 v = ((const float4*)x)[i];
        bf16x4 o;
        o[0] = (bf16_t)v.x; o[1] = (bf16_t)v.y; o[2] = (bf16_t)v.z; o[3] = (bf16_t)v.w;
        ((bf16x4*)xb)[i] = o;
    } else if (bid < 4288) {
        int idx = bid - 4096;
        transpose_tile_body(Wqkv, WqT, 1536, (idx % 24) * 64, (idx / 24) * 64, tid, T);
    } else {
        int idx = bid - 4288;
        transpose_tile_body(Wout, WoT, 512, (idx & 7) * 64, (idx >> 3) * 64, tid, T);
    }
}

// ---------------- GEMM: C[M,*] = A[M,512] * Bt[*,512]^T + bias ----------------
// m97-style: global_load_lds(16B) staging, unpadded LDS, XOR chunk swizzle
// (chunk c of row r stored at slot c ^ (r&7); applied on the global side).
// XCD-chunked block swizzle (T1): nwg%8==0 for both grids.
// MODE 0: A = xb. Q (pre-scaled 0.125*log2e) / K -> [BH][4096][64]; V -> Vt
//         [BH][64][4096] via LDS column reads. All stores 16B coalesced.
// MODE 1: A = combine(o_part, l_part) computed during staging (fused);
//         out projection -> Cout fp32 [M,512].

template <int MODE, int TN>
__global__ __launch_bounds__(256) void gemm_bt(
    const bf16_t* __restrict__ A, const bf16_t* __restrict__ Bt,
    const float* __restrict__ bias,
    bf16_t* __restrict__ Qg, bf16_t* __restrict__ Kg, bf16_t* __restrict__ Vtp,
    float* __restrict__ Cout,
    const bf16_t* __restrict__ OP, const float* __restrict__ LP)
{
    constexpr int NI = (TN == 128) ? 4 : 2;
    constexpr int NS = 4;                      // nsplit (fixed)
    __shared__ bf16_t smem[128 * 64 + TN * 64];
    __shared__ float linv_s[(MODE == 1) ? 1024 : 1];   // [hh][row], MODE 1 only
    bf16_t* As = smem;
    bf16_t* Bs = smem + 128 * 64;
    const int tid  = threadIdx.x;
    const int wid  = tid >> 6, lane = tid & 63, l16 = lane & 15, quad = lane >> 4;
    const int l8   = l16 & 7;
    const int wr   = (TN == 128) ? (wid >> 1) * 64 : wid * 32;
    const int wc   = (TN == 128) ? (wid & 1) * 64 : 0;

    // XCD-chunked swizzle: dispatch id d -> XCD d%8; XCD j owns a contiguous
    // tile range. Same-by (shared A panel) blocks land on one XCD.
    int bx, by;
    {
        const int gx  = gridDim.x;
        const int nwg = gx * gridDim.y;
        const int lin = blockIdx.y * gx + blockIdx.x;
        const int cpx = nwg >> 3;
        const int nl  = (lin & 7) * cpx + (lin >> 3);
        bx = nl % gx; by = nl / gx;
    }
    const int m0   = by * 128, n0 = bx * TN;
    const int b8   = (m0 >> 12) * 8;           // batch*8 (block-uniform)
    const int nbase0 = m0 & 4095;

    if (MODE == 1) {
        // linv[hh][row] = 1 / sum_slab l ; 1024 entries, coalesced per hh
        #pragma unroll
        for (int q = 0; q < 4; ++q) {
            int idx = tid + q * 256;
            int hh = idx >> 7, row = idx & 127;
            const float* lp = LP + (size_t)(b8 + hh) * 4096 + nbase0 + row;
            float l = 0.f;
            #pragma unroll
            for (int sl = 0; sl < NS; ++sl) l += lp[(size_t)sl * 65536];
            linv_s[idx] = 1.0f / l;
        }
    }

    f32x4 acc[NI][4] = {};

    for (int kk = 0; kk < 512; kk += 64) {
        __syncthreads();                       // readers done with LDS (+linv fill)
        if (MODE == 1) {
            // fused combine: A chunk = sum_slab(o_part)/sum_slab(l), bf16
            const int hh = kk >> 6;
            const size_t obase = (size_t)(b8 + hh) * 262144;
            #pragma unroll
            for (int i = 0; i < 4; ++i) {
                int slot = tid + i * 256;
                int row = slot >> 3, cg = (slot & 7) ^ (row & 7);
                const bf16_t* op = OP + obase + (size_t)(nbase0 + row) * 64 + cg * 8;
                float s[8] = {};
                #pragma unroll
                for (int sl = 0; sl < NS; ++sl) {
                    bf16x8 v = *(const bf16x8*)(op + (size_t)sl * 4194304);
                    #pragma unroll
                    for (int j = 0; j < 8; ++j) s[j] += (float)v[j];
                }
                const float inv = linv_s[(hh << 7) + row];
                bf16x8 o8;
                #pragma unroll
                for (int j = 0; j < 8; ++j) o8[j] = (bf16_t)(s[j] * inv);
                *(bf16x8*)&As[slot * 8] = o8;
            }
        } else {
            #pragma unroll
            for (int i = 0; i < 4; ++i) {      // A: 1024 slots (128 rows x 8 chunks)
                int slot = tid + i * 256;
                int row = slot >> 3, cg = (slot & 7) ^ (row & 7);
                gload_lds16(A + (size_t)(m0 + row) * 512 + kk + cg * 8,
                            (bf16_t*)((char*)As + ((i * 256 + (wid << 6)) << 4)));
            }
        }
        #pragma unroll
        for (int i = 0; i < TN / 32; ++i) {    // B: TN*8 slots
            int slot = tid + i * 256;
            int row = slot >> 3, cg = (slot & 7) ^ (row & 7);
            gload_lds16(Bt + (size_t)(n0 + row) * 512 + kk + cg * 8,
                        (bf16_t*)((char*)Bs + ((i * 256 + (wid << 6)) << 4)));
        }
        __syncthreads();                       // vmcnt(0)+lgkmcnt(0) drain -> staged
        #pragma unroll
        for (int s = 0; s < 2; ++s) {
            const int sw = (s * 4 + quad);
            bf16x8 a[NI], b[4];
            #pragma unroll
            for (int i = 0; i < NI; ++i) {
                int row = wr + i * 16 + l16;
                a[i] = *(const bf16x8*)&As[(row * 8 + (sw ^ l8)) * 8];
            }
            #pragma unroll
            for (int j = 0; j < 4; ++j) {
                int row = wc + j * 16 + l16;
                b[j] = *(const bf16x8*)&Bs[(row * 8 + (sw ^ l8)) * 8];
            }
            #pragma unroll
            for (int i = 0; i < NI; ++i)
                #pragma unroll
                for (int j = 0; j < 4; ++j)
                    acc[i][j] = __builtin_amdgcn_mfma_f32_16x16x32_bf16(a[i], b[j], acc[i][j], 0, 0, 0);
        }
    }

    const float qscale = 0.18033688011112042f;   // 0.125 * log2(e)

    if (MODE == 0) {
        // ---- vectorized epilogue via swizzled LDS tile E[128][128] bf16 ----
        // swizzle: chunk' = (col>>3) ^ (row&15) ^ ((row>>3)&7), bijective/row.
        __syncthreads();                       // K-loop LDS reads complete
        bf16_t* E = smem;                      // 32 KB, reuses As+Bs
        const float qs = (n0 < 512) ? qscale : 1.0f;
        #pragma unroll
        for (int i = 0; i < NI; ++i) {
            #pragma unroll
            for (int j = 0; j < 4; ++j) {
                int col = wc + j * 16 + l16;
                float bv = bias[n0 + col];
                #pragma unroll
                for (int r = 0; r < 4; ++r) {
                    int row = wr + i * 16 + quad * 4 + r;
                    int sc = (((col >> 3) ^ (row & 15) ^ ((row >> 3) & 7)) << 3) + (col & 7);
                    E[row * 128 + sc] = (bf16_t)((acc[i][j][r] + bv) * qs);
                }
            }
        }
        __syncthreads();

        const int b_ = m0 >> 12;               // whole block within one batch
        if (n0 < 1024) {
            // Q/K: row-major dest [bh][n][64]; 8 lanes cover one 128B row
            bf16_t* dst = (n0 < 512) ? Qg : Kg;
            #pragma unroll
            for (int p = 0; p < 8; ++p) {
                int g = p * 256 + tid;                 // 0..2047 chunk id
                int c = g & 7, drow = g >> 3;          // drow 0..255
                int hsel = drow >> 7, nl = drow & 127;
                int col0 = hsel * 64 + c * 8;
                int sc = (((col0 >> 3) ^ (nl & 15) ^ ((nl >> 3) & 7)) << 3);
                bf16x8 v = *(const bf16x8*)&E[nl * 128 + sc];
                int hh = ((n0 + hsel * 64) >> 6) & 7;
                int n = (m0 & 4095) + nl;
                size_t idx = (((size_t)(b_ * 8 + hh) * 4096) + n) * 64 + c * 8;
                *(bf16x8*)(dst + idx) = v;
            }
        } else {
            // V: transposed dest Vt[bh][hd][4096]; column reads from E
            #pragma unroll
            for (int p = 0; p < 8; ++p) {
                int g = p * 256 + tid;                 // 0..2047 chunk id
                int cn8 = g & 15, hdrow = g >> 4;      // hdrow 0..127
                int hsel = hdrow >> 6, hd = hdrow & 63;
                int col = hsel * 64 + hd;
                bf16x8 v;
                #pragma unroll
                for (int k = 0; k < 8; ++k) {
                    int row = cn8 * 8 + k;
                    int sc = (((col >> 3) ^ (row & 15) ^ ((row >> 3) & 7)) << 3) + (col & 7);
                    v[k] = E[row * 128 + sc];
                }
                int hh = ((n0 + hsel * 64) >> 6) & 7;
                int nbase = (m0 & 4095) + cn8 * 8;
                size_t idx = ((size_t)(b_ * 8 + hh) * 64 + hd) * 4096 + nbase;
                *(bf16x8*)(Vtp + idx) = v;
            }
        }
    } else {
        #pragma unroll
        for (int i = 0; i < NI; ++i) {
            int mrow = m0 + wr + i * 16 + quad * 4;
            #pragma unroll
            for (int j = 0; j < 4; ++j) {
                int cgl = n0 + wc + j * 16 + l16;
                float bv = bias[cgl];
                #pragma unroll
                for (int r = 0; r < 4; ++r) {
                    int m = mrow + r;
                    Cout[(size_t)m * 512 + cgl] = acc[i][j][r] + bv;
                }
            }
        }
    }
}

// ---------------- flash attention, 256-row q-blocks + split-K ----------------
// Paired strips (st, 15-st): uniform 17 tiles/block, 512 blocks @ ns=4
// (register-capped at 2 blocks/CU; combined VGPR+AGPR ~208/thread - R17).
// kt loop split: FAST (kt < 4*st, branch-free, maskless, setprio'd MFMA
// clusters) + TAIL (diag tiles, branchy mask path). P in-register via
// cvt + permlane. o_part bf16. launch_bounds(256,2): tighter spills (R10).

__global__ __launch_bounds__(256, 2) void attn_ns2(
    const bf16_t* __restrict__ Qg, const bf16_t* __restrict__ Kg,
    const bf16_t* __restrict__ Vt,
    bf16_t* __restrict__ o_part, float* __restrict__ l_part, int nsplit)
{
    __shared__ bf16_t Ks[2][64][72];
    __shared__ bf16_t Vs[2][64][72];

    const int tid  = threadIdx.x;
    const int w    = tid >> 6, lane = tid & 63, l16 = lane & 15, quad = lane >> 4;
    const int bh   = blockIdx.x & 15, pr = (blockIdx.x >> 4) & 7, h = blockIdx.x >> 7;

    bf16_t* ob = o_part + (size_t)(h * 16 + bh) * 4096 * 64;
    float*  lb = l_part + (size_t)(h * 16 + bh) * 4096;

    const int srow = tid >> 3, scol = (tid & 7) * 8;
    const int srow1 = srow + 32;
    const float MSHIFT = 12.0f;

    bf16x8 ones;
    #pragma unroll
    for (int j = 0; j < 8; ++j) ones[j] = (bf16_t)1.0f;

    uint4 kr0, kr1, vr0, vr1;

// per-tile staging: write dbuf, barrier, prefetch next, load fragments
#define TILE_PROLOGUE()                                                        \
    const int cur = kt & 1;                                                    \
    *(uint4*)&Ks[cur][srow][scol]  = kr0;                                      \
    *(uint4*)&Ks[cur][srow1][scol] = kr1;                                      \
    *(uint4*)&Vs[cur][srow][scol]  = vr0;                                      \
    *(uint4*)&Vs[cur][srow1][scol] = vr1;                                      \
    __syncthreads();                                                           \
    if (kt + 1 < b1) {                                                         \
        const size_t kb = ((size_t)bh * 4096 + (kt + 1) * 64) * 64;            \
        const size_t vb = (size_t)bh * 64 * 4096 + (kt + 1) * 64;              \
        kr0 = *(const uint4*)(Kg + kb + (size_t)srow * 64 + scol);             \
        kr1 = *(const uint4*)(Kg + kb + (size_t)srow1 * 64 + scol);            \
        vr0 = *(const uint4*)(Vt + vb + (size_t)srow * 4096 + scol);           \
        vr1 = *(const uint4*)(Vt + vb + (size_t)srow1 * 4096 + scol);          \
    }                                                                          \
    bf16x8 kf[4][2], vf[4][2];                                                 \
    _Pragma("unroll")                                                          \
    for (int cb = 0; cb < 4; ++cb) {                                           \
        kf[cb][0] = *(const bf16x8*)&Ks[cur][cb * 16 + l16][quad * 8];         \
        kf[cb][1] = *(const bf16x8*)&Ks[cur][cb * 16 + l16][32 + quad * 8];    \
    }                                                                          \
    _Pragma("unroll")                                                          \
    for (int j = 0; j < 4; ++j) {                                              \
        vf[j][0] = *(const bf16x8*)&Vs[cur][j * 16 + l16][quad * 8];           \
        vf[j][1] = *(const bf16x8*)&Vs[cur][j * 16 + l16][32 + quad * 8];      \
    }

// softmax + permlane redistribution: sv[4] (f32x4 each) -> pa0/pa1 bf16x8
#define SOFTMAX_PERMLANE(sv, pa0, pa1)                                         \
    unsigned int c_[4][2];                                                     \
    _Pragma("unroll")                                                          \
    for (int cb = 0; cb < 4; ++cb) {                                           \
        _Pragma("unroll")                                                      \
        for (int t = 0; t < 2; ++t) {                                          \
            bf16x2 pk2;                                                        \
            pk2[0] = (bf16_t)__builtin_amdgcn_exp2f(sv[cb][2 * t]     - MSHIFT); \
            pk2[1] = (bf16_t)__builtin_amdgcn_exp2f(sv[cb][2 * t + 1] - MSHIFT); \
            c_[cb][t] = __builtin_bit_cast(unsigned int, pk2);                 \
        }                                                                      \
    }                                                                          \
    unsigned int pw0[4], pw1[4];                                               \
    _Pragma("unroll")                                                          \
    for (int t = 0; t < 2; ++t) {                                              \
        auto u  = __builtin_amdgcn_permlane32_swap(c_[0][t], c_[1][t], false, false); \
        auto z  = __builtin_amdgcn_permlane16_swap(u[0], u[1], false, false);  \
        pw0[t] = z[0]; pw0[t + 2] = z[1];                                      \
        auto u2 = __builtin_amdgcn_permlane32_swap(c_[2][t], c_[3][t], false, false); \
        auto z2 = __builtin_amdgcn_permlane16_swap(u2[0], u2[1], false, false); \
        pw1[t] = z2[0]; pw1[t + 2] = z2[1];                                    \
    }                                                                          \
    uint32x4 w0v = {pw0[0], pw0[1], pw0[2], pw0[3]};                           \
    uint32x4 w1v = {pw1[0], pw1[1], pw1[2], pw1[3]};                           \
    bf16x8 pa0 = __builtin_bit_cast(bf16x8, w0v);                              \
    bf16x8 pa1 = __builtin_bit_cast(bf16x8, w1v);

    for (int ph = 0; ph < 2; ++ph) {
        const int st = ph ? (15 - pr) : pr;          // 256-row strip index
        const int T  = 4 * st + 4;
        const int b0 = (h * T) / nsplit, b1 = ((h + 1) * T) / nsplit;
        const int st4 = 4 * st;
        const int fastEnd = (st4 < b1) ? st4 : b1;

        int qrow[4];
        bf16x8 qf[4][2];
        #pragma unroll
        for (int s = 0; s < 4; ++s) {
            qrow[s] = st * 256 + s * 64 + w * 16 + l16;
            const bf16_t* qp = Qg + ((size_t)bh * 4096 + qrow[s]) * 64;
            qf[s][0] = *(const bf16x8*)(qp + quad * 8);
            qf[s][1] = *(const bf16x8*)(qp + 32 + quad * 8);
        }

        f32x4 o[4][4] = {};
        f32x4 lacc[4] = {};

        {
            const size_t kb = ((size_t)bh * 4096 + b0 * 64) * 64;
            const size_t vb = (size_t)bh * 64 * 4096 + b0 * 64;
            kr0 = *(const uint4*)(Kg + kb + (size_t)srow * 64 + scol);
            kr1 = *(const uint4*)(Kg + kb + (size_t)srow1 * 64 + scol);
            vr0 = *(const uint4*)(Vt + vb + (size_t)srow * 4096 + scol);
            vr1 = *(const uint4*)(Vt + vb + (size_t)srow1 * 4096 + scol);
        }
        __syncthreads();

        int kt = b0;

        // ---- FAST path: full tiles, no masking, branch-free across s ----
        for (; kt < fastEnd; ++kt) {
            TILE_PROLOGUE();
            #pragma unroll
            for (int s = 0; s < 4; ++s) {
                f32x4 sv[4] = {};
                __builtin_amdgcn_s_setprio(1);
                #pragma unroll
                for (int cb = 0; cb < 4; ++cb) {
                    sv[cb] = __builtin_amdgcn_mfma_f32_16x16x32_bf16(kf[cb][0], qf[s][0], sv[cb], 0, 0, 0);
                    sv[cb] = __builtin_amdgcn_mfma_f32_16x16x32_bf16(kf[cb][1], qf[s][1], sv[cb], 0, 0, 0);
                }
                __builtin_amdgcn_s_setprio(0);
                SOFTMAX_PERMLANE(sv, pa0, pa1);
                __builtin_amdgcn_s_setprio(1);
                #pragma unroll
                for (int j = 0; j < 4; ++j) {
                    o[s][j] = __builtin_amdgcn_mfma_f32_16x16x32_bf16(pa0, vf[j][0], o[s][j], 0, 0, 0);
                    o[s][j] = __builtin_amdgcn_mfma_f32_16x16x32_bf16(pa1, vf[j][1], o[s][j], 0, 0, 0);
                }
                lacc[s] = __builtin_amdgcn_mfma_f32_16x16x32_bf16(pa0, ones, lacc[s], 0, 0, 0);
                lacc[s] = __builtin_amdgcn_mfma_f32_16x16x32_bf16(pa1, ones, lacc[s], 0, 0, 0);
                __builtin_amdgcn_s_setprio(0);
            }
        }

        // ---- TAIL path: diagonal tiles (masking / partial s) ----
        for (; kt < b1; ++kt) {
            TILE_PROLOGUE();
            #pragma unroll
            for (int s = 0; s < 4; ++s) {
                const int diag = st4 + s;
                if (kt > diag) continue;

                f32x4 sv[4] = {};
                #pragma unroll
                for (int cb = 0; cb < 4; ++cb) {
                    sv[cb] = __builtin_amdgcn_mfma_f32_16x16x32_bf16(kf[cb][0], qf[s][0], sv[cb], 0, 0, 0);
                    sv[cb] = __builtin_amdgcn_mfma_f32_16x16x32_bf16(kf[cb][1], qf[s][1], sv[cb], 0, 0, 0);
                }

                if (kt == diag) {
                    #pragma unroll
                    for (int cb = 0; cb < 4; ++cb) {
                        const int keyg = kt * 64 + cb * 16 + quad * 4;
                        #pragma unroll
                        for (int r = 0; r < 4; ++r)
                            if (keyg + r > qrow[s]) sv[cb][r] = -1e30f;
                    }
                }

                SOFTMAX_PERMLANE(sv, pa0, pa1);
                #pragma unroll
                for (int j = 0; j < 4; ++j) {
                    o[s][j] = __builtin_amdgcn_mfma_f32_16x16x32_bf16(pa0, vf[j][0], o[s][j], 0, 0, 0);
                    o[s][j] = __builtin_amdgcn_mfma_f32_16x16x32_bf16(pa1, vf[j][1], o[s][j], 0, 0, 0);
                }
                lacc[s] = __builtin_amdgcn_mfma_f32_16x16x32_bf16(pa0, ones, lacc[s], 0, 0, 0);
                lacc[s] = __builtin_amdgcn_mfma_f32_16x16x32_bf16(pa1, ones, lacc[s], 0, 0, 0);
            }
        }

        #pragma unroll
        for (int s = 0; s < 4; ++s)
            #pragma unroll
            for (int r = 0; r < 4; ++r) {
                int n = st * 256 + s * 64 + w * 16 + quad * 4 + r;
                #pragma unroll
                for (int j = 0; j < 4; ++j)
                    ob[(size_t)n * 64 + j * 16 + l16] = (bf16_t)o[s][j][r];
                if (l16 == 0) lb[n] = lacc[s][r];
            }
    }
#undef TILE_PROLOGUE
#undef SOFTMAX_PERMLANE
}

// ---------------- launch ----------------

extern "C" void kernel_launch(void* const* d_in, const int* in_sizes, int n_in,
                              void* d_out, int out_size, void* d_ws, size_t ws_size,
                              hipStream_t stream) {
    const float* x    = (const float*)d_in[0];   // [2,4096,512]
    const float* Wqkv = (const float*)d_in[1];   // [512,1536]
    const float* bqkv = (const float*)d_in[2];   // [1536]
    const float* Wout = (const float*)d_in[3];   // [512,512]
    const float* bout = (const float*)d_in[4];   // [512]
    float* out = (float*)d_out;                  // [2,4096,512] fp32

    char* ws = (char*)d_ws;
    bf16_t* xb  = (bf16_t*)(ws);                 // 8 MB
    bf16_t* WqT = (bf16_t*)(ws + 8388608);       // 1.5 MB
    bf16_t* WoT = (bf16_t*)(ws + 9961472);       // 0.5 MB
    bf16_t* Qg  = (bf16_t*)(ws + 10485760);      // 8 MB (pre-scaled)
    bf16_t* Kg  = (bf16_t*)(ws + 18874368);      // 8 MB
    bf16_t* Vt  = (bf16_t*)(ws + 27262976);      // 8 MB ([bh][64][4096], written
                                                 // directly by gemm<0> epilogue)

    // o_part bf16: slab = 16*4096*64*2B = 8388608; l_part fp32 after slabs.
    // ns=4 needs 35651584 + 4*8388608 + 4*262144 = 70254592 (fits).
    const int nsplit = 4;
    bf16_t* o_part = (bf16_t*)(ws + 35651584);
    float*  l_part = (float*)(ws + 35651584 + (size_t)nsplit * 8388608);

    prep_kernel<<<4352, 256, 0, stream>>>(x, xb, Wqkv, WqT, Wout, WoT);

    gemm_bt<0, 128><<<dim3(12, 64), 256, 0, stream>>>(
        xb, WqT, bqkv, Qg, Kg, Vt, nullptr, nullptr, nullptr);

    attn_ns2<<<128 * nsplit, 256, 0, stream>>>(Qg, Kg, Vt, o_part, l_part, nsplit);

    gemm_bt<1, 128><<<dim3(4, 64), 256, 0, stream>>>(
        nullptr, WoT, bout, nullptr, nullptr, nullptr, out, o_part, l_part);
}

// Round 12
// 163.165 us; speedup vs baseline: 1.0623x; 1.0623x over previous
//
#include <hip/hip_runtime.h>
#include <hip/hip_bf16.h>

// StandardAttention: B=2, N=4096, D=512, H=8, HD=64, causal.
// R21: R20's combine-into-gemm fusion regressed (sync load->VALU->ds_write
// staging at 1 block/CU; gemm<1> ballooned more than the saved launch) ->
// reverted to R19's separate combine (measured 165.2). attn micro-pass:
// (1) setprio removed from FAST path - s_setprio is side-effecting and fences
// compiler reordering, blocking cross-s MFMA/VALU interleave (T5 null on
// phase-locked structures, m190); (2) MSHIFT folded into MFMA C-init (sv
// starts at -12) deleting 64 v_sub/tile/wave. Everything else R19-frozen.

typedef __bf16 bf16_t;
typedef __bf16 bf16x2 __attribute__((ext_vector_type(2)));
typedef __bf16 bf16x4 __attribute__((ext_vector_type(4)));
typedef __bf16 bf16x8 __attribute__((ext_vector_type(8)));
typedef float  f32x4  __attribute__((ext_vector_type(4)));
typedef unsigned int uint32x4 __attribute__((ext_vector_type(4)));

// async global->LDS, 16 B per lane; lds dst must be wave-uniform base (HW puts
// lane i at base + i*16)
__device__ __forceinline__ void gload_lds16(const bf16_t* g, bf16_t* l) {
    __builtin_amdgcn_global_load_lds(
        (const __attribute__((address_space(1))) void*)g,
        (__attribute__((address_space(3))) void*)l, 16, 0, 0);
}

// ---------------- fused prep: x->bf16 convert + both weight transposes ------
// blocks [0,4096): convert x (fp32->bf16, float4/lane)
// blocks [4096,4288): Wqkv [512][1536] -> WqT [1536][512] bf16 (64x64 tiles)
// blocks [4288,4352): Wout [512][512]  -> WoT [512][512]  bf16

__device__ __forceinline__ void transpose_tile_body(
    const float* __restrict__ in, bf16_t* __restrict__ out, int N,
    int n0, int k0, int tid, bf16_t (*T)[72])
{
    #pragma unroll
    for (int pass = 0; pass < 4; ++pass) {
        int kk = pass * 16 + (tid >> 4), nn = (tid & 15) * 4;
        float4 v = *(const float4*)(in + (size_t)(k0 + kk) * N + n0 + nn);
        T[nn + 0][kk] = (bf16_t)v.x; T[nn + 1][kk] = (bf16_t)v.y;
        T[nn + 2][kk] = (bf16_t)v.z; T[nn + 3][kk] = (bf16_t)v.w;
    }
    __syncthreads();
    #pragma unroll
    for (int pass = 0; pass < 2; ++pass) {
        int n = pass * 32 + (tid >> 3), c8 = (tid & 7) * 8;
        *(bf16x8*)(out + (size_t)(n0 + n) * 512 + k0 + c8) = *(const bf16x8*)&T[n][c8];
    }
}

__global__ void prep_kernel(const float* __restrict__ x, bf16_t* __restrict__ xb,
                            const float* __restrict__ Wqkv, bf16_t* __restrict__ WqT,
                            const float* __restrict__ Wout, bf16_t* __restrict__ WoT)
{
    __shared__ bf16_t T[64][72];
    const int bid = blockIdx.x, tid = threadIdx.x;
    if (bid < 4096) {
        int i = bid * 256 + tid;
        float4 v = ((const float4*)x)[i];
        bf16x4 o;
        o[0] = (bf16_t)v.x; o[1] = (bf16_t)v.y; o[2] = (bf16_t)v.z; o[3] = (bf16_t)v.w;
        ((bf16x4*)xb)[i] = o;
    } else if (bid < 4288) {
        int idx = bid - 4096;
        transpose_tile_body(Wqkv, WqT, 1536, (idx % 24) * 64, (idx / 24) * 64, tid, T);
    } else {
        int idx = bid - 4288;
        transpose_tile_body(Wout, WoT, 512, (idx & 7) * 64, (idx >> 3) * 64, tid, T);
    }
}

// ---------------- GEMM: C[M,*] = A[M,512] * Bt[*,512]^T + bias ----------------
// m97-style: global_load_lds(16B) staging, unpadded LDS, XOR chunk swizzle
// (chunk c of row r stored at slot c ^ (r&7); applied on the global side).
// XCD-chunked block swizzle (T1): nwg%8==0 for both grids; same-by blocks
// (shared A panel) land on one XCD.
// MODE 0: QKV. Blocks are dest-uniform (which = bx>>2): Q (pre-scaled
//         0.125*log2e) and K -> [BH][4096][64]; V -> Vt [BH][64][4096] via
//         LDS column reads (transposed write). All stores 16B coalesced.
// MODE 1: out projection -> Cout fp32 [M,512] (scalar f32 stores)

template <int MODE, int TN>
__global__ __launch_bounds__(256) void gemm_bt(
    const bf16_t* __restrict__ A, const bf16_t* __restrict__ Bt,
    const float* __restrict__ bias,
    bf16_t* __restrict__ Qg, bf16_t* __restrict__ Kg, bf16_t* __restrict__ Vtp,
    float* __restrict__ Cout)
{
    constexpr int NI = (TN == 128) ? 4 : 2;
    __shared__ bf16_t smem[128 * 64 + TN * 64];
    bf16_t* As = smem;
    bf16_t* Bs = smem + 128 * 64;
    const int tid  = threadIdx.x;
    const int wid  = tid >> 6, lane = tid & 63, l16 = lane & 15, quad = lane >> 4;
    const int l8   = l16 & 7;
    const int wr   = (TN == 128) ? (wid >> 1) * 64 : wid * 32;
    const int wc   = (TN == 128) ? (wid & 1) * 64 : 0;

    // XCD-chunked swizzle: dispatch id d -> XCD d%8; XCD j owns a contiguous
    // tile range. Same-by (shared A panel) blocks land on one XCD.
    int bx, by;
    {
        const int gx  = gridDim.x;
        const int nwg = gx * gridDim.y;
        const int lin = blockIdx.y * gx + blockIdx.x;
        const int cpx = nwg >> 3;
        const int nl  = (lin & 7) * cpx + (lin >> 3);
        bx = nl % gx; by = nl / gx;
    }
    const int m0   = by * 128, n0 = bx * TN;

    f32x4 acc[NI][4] = {};

    for (int kk = 0; kk < 512; kk += 64) {
        __syncthreads();                       // readers done with LDS
        #pragma unroll
        for (int i = 0; i < 4; ++i) {          // A: 1024 slots (128 rows x 8 chunks)
            int slot = tid + i * 256;
            int row = slot >> 3, cg = (slot & 7) ^ (row & 7);
            gload_lds16(A + (size_t)(m0 + row) * 512 + kk + cg * 8,
                        (bf16_t*)((char*)As + ((i * 256 + (wid << 6)) << 4)));
        }
        #pragma unroll
        for (int i = 0; i < TN / 32; ++i) {    // B: TN*8 slots
            int slot = tid + i * 256;
            int row = slot >> 3, cg = (slot & 7) ^ (row & 7);
            gload_lds16(Bt + (size_t)(n0 + row) * 512 + kk + cg * 8,
                        (bf16_t*)((char*)Bs + ((i * 256 + (wid << 6)) << 4)));
        }
        __syncthreads();                       // vmcnt(0) drain -> staged
        #pragma unroll
        for (int s = 0; s < 2; ++s) {
            const int sw = (s * 4 + quad);
            bf16x8 a[NI], b[4];
            #pragma unroll
            for (int i = 0; i < NI; ++i) {
                int row = wr + i * 16 + l16;
                a[i] = *(const bf16x8*)&As[(row * 8 + (sw ^ l8)) * 8];
            }
            #pragma unroll
            for (int j = 0; j < 4; ++j) {
                int row = wc + j * 16 + l16;
                b[j] = *(const bf16x8*)&Bs[(row * 8 + (sw ^ l8)) * 8];
            }
            #pragma unroll
            for (int i = 0; i < NI; ++i)
                #pragma unroll
                for (int j = 0; j < 4; ++j)
                    acc[i][j] = __builtin_amdgcn_mfma_f32_16x16x32_bf16(a[i], b[j], acc[i][j], 0, 0, 0);
        }
    }

    const float qscale = 0.18033688011112042f;   // 0.125 * log2(e)

    if (MODE == 0) {
        // ---- vectorized epilogue via swizzled LDS tile E[128][128] bf16 ----
        // swizzle: chunk' = (col>>3) ^ (row&15) ^ ((row>>3)&7), bijective/row.
        __syncthreads();                       // K-loop LDS reads complete
        bf16_t* E = smem;                      // 32 KB, reuses As+Bs
        const float qs = (n0 < 512) ? qscale : 1.0f;
        #pragma unroll
        for (int i = 0; i < NI; ++i) {
            #pragma unroll
            for (int j = 0; j < 4; ++j) {
                int col = wc + j * 16 + l16;
                float bv = bias[n0 + col];
                #pragma unroll
                for (int r = 0; r < 4; ++r) {
                    int row = wr + i * 16 + quad * 4 + r;
                    int sc = (((col >> 3) ^ (row & 15) ^ ((row >> 3) & 7)) << 3) + (col & 7);
                    E[row * 128 + sc] = (bf16_t)((acc[i][j][r] + bv) * qs);
                }
            }
        }
        __syncthreads();

        const int b_ = m0 >> 12;               // whole block within one batch
        if (n0 < 1024) {
            // Q/K: row-major dest [bh][n][64]; 8 lanes cover one 128B row
            bf16_t* dst = (n0 < 512) ? Qg : Kg;
            #pragma unroll
            for (int p = 0; p < 8; ++p) {
                int g = p * 256 + tid;                 // 0..2047 chunk id
                int c = g & 7, drow = g >> 3;          // drow 0..255
                int hsel = drow >> 7, nl = drow & 127;
                int col0 = hsel * 64 + c * 8;
                int sc = (((col0 >> 3) ^ (nl & 15) ^ ((nl >> 3) & 7)) << 3);
                bf16x8 v = *(const bf16x8*)&E[nl * 128 + sc];
                int hh = ((n0 + hsel * 64) >> 6) & 7;
                int n = (m0 & 4095) + nl;
                size_t idx = (((size_t)(b_ * 8 + hh) * 4096) + n) * 64 + c * 8;
                *(bf16x8*)(dst + idx) = v;
            }
        } else {
            // V: transposed dest Vt[bh][hd][4096]; column reads from E
            #pragma unroll
            for (int p = 0; p < 8; ++p) {
                int g = p * 256 + tid;                 // 0..2047 chunk id
                int cn8 = g & 15, hdrow = g >> 4;      // hdrow 0..127
                int hsel = hdrow >> 6, hd = hdrow & 63;
                int col = hsel * 64 + hd;
                bf16x8 v;
                #pragma unroll
                for (int k = 0; k < 8; ++k) {
                    int row = cn8 * 8 + k;
                    int sc = (((col >> 3) ^ (row & 15) ^ ((row >> 3) & 7)) << 3) + (col & 7);
                    v[k] = E[row * 128 + sc];
                }
                int hh = ((n0 + hsel * 64) >> 6) & 7;
                int nbase = (m0 & 4095) + cn8 * 8;
                size_t idx = ((size_t)(b_ * 8 + hh) * 64 + hd) * 4096 + nbase;
                *(bf16x8*)(Vtp + idx) = v;
            }
        }
    } else {
        #pragma unroll
        for (int i = 0; i < NI; ++i) {
            int mrow = m0 + wr + i * 16 + quad * 4;
            #pragma unroll
            for (int j = 0; j < 4; ++j) {
                int cgl = n0 + wc + j * 16 + l16;
                float bv = bias[cgl];
                #pragma unroll
                for (int r = 0; r < 4; ++r) {
                    int m = mrow + r;
                    Cout[(size_t)m * 512 + cgl] = acc[i][j][r] + bv;
                }
            }
        }
    }
}

// ---------------- flash attention, 256-row q-blocks + split-K ----------------
// Paired strips (st, 15-st): uniform 17 tiles/block, 512 blocks @ ns=4
// (register-capped at 2 blocks/CU; combined VGPR+AGPR ~208/thread - R17).
// kt loop split: FAST (kt < 4*st, branch-free, maskless; NO setprio - it
// fences compiler cross-s interleave) + TAIL (diag tiles, branchy mask path).
// MSHIFT folded into MFMA C-init (sv starts at -12). P in-register via
// cvt + permlane. o_part bf16. launch_bounds(256,2): tighter spills (R10).

__global__ __launch_bounds__(256, 2) void attn_ns2(
    const bf16_t* __restrict__ Qg, const bf16_t* __restrict__ Kg,
    const bf16_t* __restrict__ Vt,
    bf16_t* __restrict__ o_part, float* __restrict__ l_part, int nsplit)
{
    __shared__ bf16_t Ks[2][64][72];
    __shared__ bf16_t Vs[2][64][72];

    const int tid  = threadIdx.x;
    const int w    = tid >> 6, lane = tid & 63, l16 = lane & 15, quad = lane >> 4;
    const int bh   = blockIdx.x & 15, pr = (blockIdx.x >> 4) & 7, h = blockIdx.x >> 7;

    bf16_t* ob = o_part + (size_t)(h * 16 + bh) * 4096 * 64;
    float*  lb = l_part + (size_t)(h * 16 + bh) * 4096;

    const int srow = tid >> 3, scol = (tid & 7) * 8;
    const int srow1 = srow + 32;
    const float MSHIFT = 12.0f;

    bf16x8 ones;
    #pragma unroll
    for (int j = 0; j < 8; ++j) ones[j] = (bf16_t)1.0f;

    uint4 kr0, kr1, vr0, vr1;

// per-tile staging: write dbuf, barrier, prefetch next, load fragments
#define TILE_PROLOGUE()                                                        \
    const int cur = kt & 1;                                                    \
    *(uint4*)&Ks[cur][srow][scol]  = kr0;                                      \
    *(uint4*)&Ks[cur][srow1][scol] = kr1;                                      \
    *(uint4*)&Vs[cur][srow][scol]  = vr0;                                      \
    *(uint4*)&Vs[cur][srow1][scol] = vr1;                                      \
    __syncthreads();                                                           \
    if (kt + 1 < b1) {                                                         \
        const size_t kb = ((size_t)bh * 4096 + (kt + 1) * 64) * 64;            \
        const size_t vb = (size_t)bh * 64 * 4096 + (kt + 1) * 64;              \
        kr0 = *(const uint4*)(Kg + kb + (size_t)srow * 64 + scol);             \
        kr1 = *(const uint4*)(Kg + kb + (size_t)srow1 * 64 + scol);            \
        vr0 = *(const uint4*)(Vt + vb + (size_t)srow * 4096 + scol);           \
        vr1 = *(const uint4*)(Vt + vb + (size_t)srow1 * 4096 + scol);          \
    }                                                                          \
    bf16x8 kf[4][2], vf[4][2];                                                 \
    _Pragma("unroll")                                                          \
    for (int cb = 0; cb < 4; ++cb) {                                           \
        kf[cb][0] = *(const bf16x8*)&Ks[cur][cb * 16 + l16][quad * 8];         \
        kf[cb][1] = *(const bf16x8*)&Ks[cur][cb * 16 + l16][32 + quad * 8];    \
    }                                                                          \
    _Pragma("unroll")                                                          \
    for (int j = 0; j < 4; ++j) {                                              \
        vf[j][0] = *(const bf16x8*)&Vs[cur][j * 16 + l16][quad * 8];           \
        vf[j][1] = *(const bf16x8*)&Vs[cur][j * 16 + l16][32 + quad * 8];      \
    }

// softmax + permlane redistribution: sv[4] (f32x4, pre-shifted by -MSHIFT via
// C-init) -> pa0/pa1 bf16x8
#define SOFTMAX_PERMLANE(sv, pa0, pa1)                                         \
    unsigned int c_[4][2];                                                     \
    _Pragma("unroll")                                                          \
    for (int cb = 0; cb < 4; ++cb) {                                           \
        _Pragma("unroll")                                                      \
        for (int t = 0; t < 2; ++t) {                                          \
            bf16x2 pk2;                                                        \
            pk2[0] = (bf16_t)__builtin_amdgcn_exp2f(sv[cb][2 * t]);            \
            pk2[1] = (bf16_t)__builtin_amdgcn_exp2f(sv[cb][2 * t + 1]);        \
            c_[cb][t] = __builtin_bit_cast(unsigned int, pk2);                 \
        }                                                                      \
    }                                                                          \
    unsigned int pw0[4], pw1[4];                                               \
    _Pragma("unroll")                                                          \
    for (int t = 0; t < 2; ++t) {                                              \
        auto u  = __builtin_amdgcn_permlane32_swap(c_[0][t], c_[1][t], false, false); \
        auto z  = __builtin_amdgcn_permlane16_swap(u[0], u[1], false, false);  \
        pw0[t] = z[0]; pw0[t + 2] = z[1];                                      \
        auto u2 = __builtin_amdgcn_permlane32_swap(c_[2][t], c_[3][t], false, false); \
        auto z2 = __builtin_amdgcn_permlane16_swap(u2[0], u2[1], false, false); \
        pw1[t] = z2[0]; pw1[t + 2] = z2[1];                                    \
    }                                                                          \
    uint32x4 w0v = {pw0[0], pw0[1], pw0[2], pw0[3]};                           \
    uint32x4 w1v = {pw1[0], pw1[1], pw1[2], pw1[3]};                           \
    bf16x8 pa0 = __builtin_bit_cast(bf16x8, w0v);                              \
    bf16x8 pa1 = __builtin_bit_cast(bf16x8, w1v);

    for (int ph = 0; ph < 2; ++ph) {
        const int st = ph ? (15 - pr) : pr;          // 256-row strip index
        const int T  = 4 * st + 4;
        const int b0 = (h * T) / nsplit, b1 = ((h + 1) * T) / nsplit;
        const int st4 = 4 * st;
        const int fastEnd = (st4 < b1) ? st4 : b1;

        int qrow[4];
        bf16x8 qf[4][2];
        #pragma unroll
        for (int s = 0; s < 4; ++s) {
            qrow[s] = st * 256 + s * 64 + w * 16 + l16;
            const bf16_t* qp = Qg + ((size_t)bh * 4096 + qrow[s]) * 64;
            qf[s][0] = *(const bf16x8*)(qp + quad * 8);
            qf[s][1] = *(const bf16x8*)(qp + 32 + quad * 8);
        }

        f32x4 o[4][4] = {};
        f32x4 lacc[4] = {};

        {
            const size_t kb = ((size_t)bh * 4096 + b0 * 64) * 64;
            const size_t vb = (size_t)bh * 64 * 4096 + b0 * 64;
            kr0 = *(const uint4*)(Kg + kb + (size_t)srow * 64 + scol);
            kr1 = *(const uint4*)(Kg + kb + (size_t)srow1 * 64 + scol);
            vr0 = *(const uint4*)(Vt + vb + (size_t)srow * 4096 + scol);
            vr1 = *(const uint4*)(Vt + vb + (size_t)srow1 * 4096 + scol);
        }
        __syncthreads();

        int kt = b0;

        // ---- FAST path: full tiles, no masking, branch-free across s ----
        for (; kt < fastEnd; ++kt) {
            TILE_PROLOGUE();
            #pragma unroll
            for (int s = 0; s < 4; ++s) {
                f32x4 sv[4];
                #pragma unroll
                for (int cb = 0; cb < 4; ++cb)
                    sv[cb] = f32x4{-MSHIFT, -MSHIFT, -MSHIFT, -MSHIFT};
                #pragma unroll
                for (int cb = 0; cb < 4; ++cb) {
                    sv[cb] = __builtin_amdgcn_mfma_f32_16x16x32_bf16(kf[cb][0], qf[s][0], sv[cb], 0, 0, 0);
                    sv[cb] = __builtin_amdgcn_mfma_f32_16x16x32_bf16(kf[cb][1], qf[s][1], sv[cb], 0, 0, 0);
                }
                SOFTMAX_PERMLANE(sv, pa0, pa1);
                #pragma unroll
                for (int j = 0; j < 4; ++j) {
                    o[s][j] = __builtin_amdgcn_mfma_f32_16x16x32_bf16(pa0, vf[j][0], o[s][j], 0, 0, 0);
                    o[s][j] = __builtin_amdgcn_mfma_f32_16x16x32_bf16(pa1, vf[j][1], o[s][j], 0, 0, 0);
                }
                lacc[s] = __builtin_amdgcn_mfma_f32_16x16x32_bf16(pa0, ones, lacc[s], 0, 0, 0);
                lacc[s] = __builtin_amdgcn_mfma_f32_16x16x32_bf16(pa1, ones, lacc[s], 0, 0, 0);
            }
        }

        // ---- TAIL path: diagonal tiles (masking / partial s) ----
        for (; kt < b1; ++kt) {
            TILE_PROLOGUE();
            #pragma unroll
            for (int s = 0; s < 4; ++s) {
                const int diag = st4 + s;
                if (kt > diag) continue;

                f32x4 sv[4];
                #pragma unroll
                for (int cb = 0; cb < 4; ++cb)
                    sv[cb] = f32x4{-MSHIFT, -MSHIFT, -MSHIFT, -MSHIFT};
                #pragma unroll
                for (int cb = 0; cb < 4; ++cb) {
                    sv[cb] = __builtin_amdgcn_mfma_f32_16x16x32_bf16(kf[cb][0], qf[s][0], sv[cb], 0, 0, 0);
                    sv[cb] = __builtin_amdgcn_mfma_f32_16x16x32_bf16(kf[cb][1], qf[s][1], sv[cb], 0, 0, 0);
                }

                if (kt == diag) {
                    #pragma unroll
                    for (int cb = 0; cb < 4; ++cb) {
                        const int keyg = kt * 64 + cb * 16 + quad * 4;
                        #pragma unroll
                        for (int r = 0; r < 4; ++r)
                            if (keyg + r > qrow[s]) sv[cb][r] = -1e30f;
                    }
                }

                SOFTMAX_PERMLANE(sv, pa0, pa1);
                #pragma unroll
                for (int j = 0; j < 4; ++j) {
                    o[s][j] = __builtin_amdgcn_mfma_f32_16x16x32_bf16(pa0, vf[j][0], o[s][j], 0, 0, 0);
                    o[s][j] = __builtin_amdgcn_mfma_f32_16x16x32_bf16(pa1, vf[j][1], o[s][j], 0, 0, 0);
                }
                lacc[s] = __builtin_amdgcn_mfma_f32_16x16x32_bf16(pa0, ones, lacc[s], 0, 0, 0);
                lacc[s] = __builtin_amdgcn_mfma_f32_16x16x32_bf16(pa1, ones, lacc[s], 0, 0, 0);
            }
        }

        #pragma unroll
        for (int s = 0; s < 4; ++s)
            #pragma unroll
            for (int r = 0; r < 4; ++r) {
                int n = st * 256 + s * 64 + w * 16 + quad * 4 + r;
                #pragma unroll
                for (int j = 0; j < 4; ++j)
                    ob[(size_t)n * 64 + j * 16 + l16] = (bf16_t)o[s][j][r];
                if (l16 == 0) lb[n] = lacc[s][r];
            }
    }
#undef TILE_PROLOGUE
#undef SOFTMAX_PERMLANE
}

// combine: Og[b][n][hh*64+hd] = sum_h(o_h) / sum_h(l_h), bf16 (o_part bf16)
__global__ void combine_kernel(const bf16_t* __restrict__ o_part,
                               const float* __restrict__ l_part,
                               bf16_t* __restrict__ Og, int ns)
{
    int t = blockIdx.x * 256 + threadIdx.x;
    int oct = t & 7, n = (t >> 3) & 4095, bh = t >> 15;
    size_t base = ((size_t)bh * 4096 + n) * 64 + oct * 8;
    float s[8] = {};
    float l = 0.f;
    for (int h = 0; h < ns; ++h) {
        bf16x8 v = *(const bf16x8*)(o_part + (size_t)h * 16 * 4096 * 64 + base);
        #pragma unroll
        for (int j = 0; j < 8; ++j) s[j] += (float)v[j];
        l += l_part[(size_t)h * 16 * 4096 + (size_t)bh * 4096 + n];
    }
    float inv = 1.0f / l;
    bf16x8 res;
    #pragma unroll
    for (int j = 0; j < 8; ++j) res[j] = (bf16_t)(s[j] * inv);
    *(bf16x8*)(Og + ((size_t)((bh >> 3) * 4096 + n)) * 512 + (bh & 7) * 64 + oct * 8) = res;
}

// ---------------- launch ----------------

extern "C" void kernel_launch(void* const* d_in, const int* in_sizes, int n_in,
                              void* d_out, int out_size, void* d_ws, size_t ws_size,
                              hipStream_t stream) {
    const float* x    = (const float*)d_in[0];   // [2,4096,512]
    const float* Wqkv = (const float*)d_in[1];   // [512,1536]
    const float* bqkv = (const float*)d_in[2];   // [1536]
    const float* Wout = (const float*)d_in[3];   // [512,512]
    const float* bout = (const float*)d_in[4];   // [512]
    float* out = (float*)d_out;                  // [2,4096,512] fp32

    char* ws = (char*)d_ws;
    bf16_t* xb  = (bf16_t*)(ws);                 // 8 MB (reused as Og)
    bf16_t* WqT = (bf16_t*)(ws + 8388608);       // 1.5 MB
    bf16_t* WoT = (bf16_t*)(ws + 9961472);       // 0.5 MB
    bf16_t* Qg  = (bf16_t*)(ws + 10485760);      // 8 MB (pre-scaled)
    bf16_t* Kg  = (bf16_t*)(ws + 18874368);      // 8 MB
    bf16_t* Vt  = (bf16_t*)(ws + 27262976);      // 8 MB ([bh][64][4096], written
                                                 // directly by gemm<0> epilogue)

    // o_part bf16: slab = 16*4096*64*2B = 8388608; l_part fp32 after slabs.
    // ns=4 needs 35651584 + 4*8388608 + 4*262144 = 70254592 (fits).
    const int nsplit = 4;
    bf16_t* o_part = (bf16_t*)(ws + 35651584);
    float*  l_part = (float*)(ws + 35651584 + (size_t)nsplit * 8388608);

    prep_kernel<<<4352, 256, 0, stream>>>(x, xb, Wqkv, WqT, Wout, WoT);

    gemm_bt<0, 128><<<dim3(12, 64), 256, 0, stream>>>(
        xb, WqT, bqkv, Qg, Kg, Vt, nullptr);

    attn_ns2<<<128 * nsplit, 256, 0, stream>>>(Qg, Kg, Vt, o_part, l_part, nsplit);
    combine_kernel<<<2048, 256, 0, stream>>>(o_part, l_part, xb /* Og */, nsplit);

    gemm_bt<1, 64><<<dim3(8, 64), 256, 0, stream>>>(
        xb, WoT, bout, nullptr, nullptr, nullptr, out);
}

// Round 13
// 162.480 us; speedup vs baseline: 1.0668x; 1.0042x over previous
//
#include <hip/hip_runtime.h>
#include <hip/hip_bf16.h>

// StandardAttention: B=2, N=4096, D=512, H=8, HD=64, causal.
// R22: combine->gemm<1> fusion, take 2 (R20 failed: SYNC staging at 1
// block/CU). Fix = T14 async-split: o_part slab loads go to REGISTERS one
// K-step ahead (issued post-barrier, fly under MFMA); staging window only
// holds sum/scale/cvt + 4 ds_writes. TN=64 keeps 512 blocks (2+/CU). XCD
// swizzle makes the 8 col-blocks per A-panel L2-resident. Deletes combine
// launch + 16MB Og round-trip. attn (R21: 46.8us) / gemm<0> / prep frozen.

typedef __bf16 bf16_t;
typedef __bf16 bf16x2 __attribute__((ext_vector_type(2)));
typedef __bf16 bf16x4 __attribute__((ext_vector_type(4)));
typedef __bf16 bf16x8 __attribute__((ext_vector_type(8)));
typedef float  f32x4  __attribute__((ext_vector_type(4)));
typedef unsigned int uint32x4 __attribute__((ext_vector_type(4)));

// async global->LDS, 16 B per lane; lds dst must be wave-uniform base (HW puts
// lane i at base + i*16)
__device__ __forceinline__ void gload_lds16(const bf16_t* g, bf16_t* l) {
    __builtin_amdgcn_global_load_lds(
        (const __attribute__((address_space(1))) void*)g,
        (__attribute__((address_space(3))) void*)l, 16, 0, 0);
}

// ---------------- fused prep: x->bf16 convert + both weight transposes ------
// blocks [0,4096): convert x (fp32->bf16, float4/lane)
// blocks [4096,4288): Wqkv [512][1536] -> WqT [1536][512] bf16 (64x64 tiles)
// blocks [4288,4352): Wout [512][512]  -> WoT [512][512]  bf16

__device__ __forceinline__ void transpose_tile_body(
    const float* __restrict__ in, bf16_t* __restrict__ out, int N,
    int n0, int k0, int tid, bf16_t (*T)[72])
{
    #pragma unroll
    for (int pass = 0; pass < 4; ++pass) {
        int kk = pass * 16 + (tid >> 4), nn = (tid & 15) * 4;
        float4 v = *(const float4*)(in + (size_t)(k0 + kk) * N + n0 + nn);
        T[nn + 0][kk] = (bf16_t)v.x; T[nn + 1][kk] = (bf16_t)v.y;
        T[nn + 2][kk] = (bf16_t)v.z; T[nn + 3][kk] = (bf16_t)v.w;
    }
    __syncthreads();
    #pragma unroll
    for (int pass = 0; pass < 2; ++pass) {
        int n = pass * 32 + (tid >> 3), c8 = (tid & 7) * 8;
        *(bf16x8*)(out + (size_t)(n0 + n) * 512 + k0 + c8) = *(const bf16x8*)&T[n][c8];
    }
}

__global__ void prep_kernel(const float* __restrict__ x, bf16_t* __restrict__ xb,
                            const float* __restrict__ Wqkv, bf16_t* __restrict__ WqT,
                            const float* __restrict__ Wout, bf16_t* __restrict__ WoT)
{
    __shared__ bf16_t T[64][72];
    const int bid = blockIdx.x, tid = threadIdx.x;
    if (bid < 4096) {
        int i = bid * 256 + tid;
        float4 v = ((const float4*)x)[i];
        bf16x4 o;
        o[0] = (bf16_t)v.x; o[1] = (bf16_t)v.y; o[2] = (bf16_t)v.z; o[3] = (bf16_t)v.w;
        ((bf16x4*)xb)[i] = o;
    } else if (bid < 4288) {
        int idx = bid - 4096;
        transpose_tile_body(Wqkv, WqT, 1536, (idx % 24) * 64, (idx / 24) * 64, tid, T);
    } else {
        int idx = bid - 4288;
        transpose_tile_body(Wout, WoT, 512, (idx & 7) * 64, (idx >> 3) * 64, tid, T);
    }
}

// ---------------- GEMM: C[M,*] = A[M,512] * Bt[*,512]^T + bias ----------------
// m97-style: global_load_lds(16B) staging, unpadded LDS, XOR chunk swizzle
// (chunk c of row r stored at slot c ^ (r&7); applied on the global side).
// XCD-chunked block swizzle (T1): nwg%8==0 for both grids.
// MODE 0: A = xb. Q (pre-scaled 0.125*log2e) / K -> [BH][4096][64]; V -> Vt
//         [BH][64][4096] via LDS column reads. All stores 16B coalesced.
// MODE 1: A = combine(o_part, l_part), staged via register prefetch one
//         K-step ahead (async-split); out projection -> Cout fp32 [M,512].

template <int MODE, int TN>
__global__ __launch_bounds__(256) void gemm_bt(
    const bf16_t* __restrict__ A, const bf16_t* __restrict__ Bt,
    const float* __restrict__ bias,
    bf16_t* __restrict__ Qg, bf16_t* __restrict__ Kg, bf16_t* __restrict__ Vtp,
    float* __restrict__ Cout,
    const bf16_t* __restrict__ OP, const float* __restrict__ LP)
{
    constexpr int NI = (TN == 128) ? 4 : 2;
    constexpr int NS = 4;                      // nsplit (fixed)
    __shared__ bf16_t smem[128 * 64 + TN * 64];
    __shared__ float linv_s[(MODE == 1) ? 1024 : 1];   // [hh][row], MODE 1 only
    bf16_t* As = smem;
    bf16_t* Bs = smem + 128 * 64;
    const int tid  = threadIdx.x;
    const int wid  = tid >> 6, lane = tid & 63, l16 = lane & 15, quad = lane >> 4;
    const int l8   = l16 & 7;
    const int wr   = (TN == 128) ? (wid >> 1) * 64 : wid * 32;
    const int wc   = (TN == 128) ? (wid & 1) * 64 : 0;

    // XCD-chunked swizzle: dispatch id d -> XCD d%8; XCD j owns a contiguous
    // tile range. Same-by (shared A panel) blocks land on one XCD.
    int bx, by;
    {
        const int gx  = gridDim.x;
        const int nwg = gx * gridDim.y;
        const int lin = blockIdx.y * gx + blockIdx.x;
        const int cpx = nwg >> 3;
        const int nl  = (lin & 7) * cpx + (lin >> 3);
        bx = nl % gx; by = nl / gx;
    }
    const int m0   = by * 128, n0 = bx * TN;
    const int b8   = (m0 >> 12) * 8;           // batch*8 (block-uniform)
    const int nbase0 = m0 & 4095;

    bf16x8 aw[4][NS];                          // MODE 1 register A-prefetch

    if (MODE == 1) {
        // linv[hh][row] = 1 / sum_slab l ; 1024 entries
        #pragma unroll
        for (int q = 0; q < 4; ++q) {
            int idx = tid + q * 256;
            int hh = idx >> 7, row = idx & 127;
            const float* lp = LP + (size_t)(b8 + hh) * 4096 + nbase0 + row;
            float l = 0.f;
            #pragma unroll
            for (int sl = 0; sl < NS; ++sl) l += lp[(size_t)sl * 65536];
            linv_s[idx] = 1.0f / l;
        }
        // prefetch A for kk=0 (hh=0)
        const size_t obase = (size_t)b8 * 262144;
        #pragma unroll
        for (int i = 0; i < 4; ++i) {
            int slot = tid + i * 256;
            int row = slot >> 3, cg = (slot & 7) ^ (row & 7);
            const bf16_t* op = OP + obase + (size_t)(nbase0 + row) * 64 + cg * 8;
            #pragma unroll
            for (int sl = 0; sl < NS; ++sl)
                aw[i][sl] = *(const bf16x8*)(op + (size_t)sl * 4194304);
        }
    }

    f32x4 acc[NI][4] = {};

    for (int kk = 0; kk < 512; kk += 64) {
        __syncthreads();                       // readers done with LDS (+linv fill)
        if (MODE == 1) {
            #pragma unroll
            for (int i = 0; i < TN / 32; ++i) {    // B: TN*8 slots (async)
                int slot = tid + i * 256;
                int row = slot >> 3, cg = (slot & 7) ^ (row & 7);
                gload_lds16(Bt + (size_t)(n0 + row) * 512 + kk + cg * 8,
                            (bf16_t*)((char*)Bs + ((i * 256 + (wid << 6)) << 4)));
            }
            // consume prefetched A regs: sum slabs, scale, cvt, ds_write
            const int hh = kk >> 6;
            #pragma unroll
            for (int i = 0; i < 4; ++i) {
                int slot = tid + i * 256;
                int row = slot >> 3;
                float s8[8] = {};
                #pragma unroll
                for (int sl = 0; sl < NS; ++sl)
                    #pragma unroll
                    for (int j = 0; j < 8; ++j) s8[j] += (float)aw[i][sl][j];
                const float inv = linv_s[(hh << 7) + row];
                bf16x8 o8;
                #pragma unroll
                for (int j = 0; j < 8; ++j) o8[j] = (bf16_t)(s8[j] * inv);
                *(bf16x8*)&As[slot * 8] = o8;
            }
        } else {
            #pragma unroll
            for (int i = 0; i < 4; ++i) {      // A: 1024 slots (128 rows x 8 chunks)
                int slot = tid + i * 256;
                int row = slot >> 3, cg = (slot & 7) ^ (row & 7);
                gload_lds16(A + (size_t)(m0 + row) * 512 + kk + cg * 8,
                            (bf16_t*)((char*)As + ((i * 256 + (wid << 6)) << 4)));
            }
            #pragma unroll
            for (int i = 0; i < TN / 32; ++i) {    // B: TN*8 slots
                int slot = tid + i * 256;
                int row = slot >> 3, cg = (slot & 7) ^ (row & 7);
                gload_lds16(Bt + (size_t)(n0 + row) * 512 + kk + cg * 8,
                            (bf16_t*)((char*)Bs + ((i * 256 + (wid << 6)) << 4)));
            }
        }
        __syncthreads();                       // vmcnt/lgkm drain -> staged

        if (MODE == 1 && kk + 64 < 512) {      // issue next A prefetch; flies
            const int hh2 = (kk >> 6) + 1;     // under the MFMA phase below
            const size_t obase = (size_t)(b8 + hh2) * 262144;
            #pragma unroll
            for (int i = 0; i < 4; ++i) {
                int slot = tid + i * 256;
                int row = slot >> 3, cg = (slot & 7) ^ (row & 7);
                const bf16_t* op = OP + obase + (size_t)(nbase0 + row) * 64 + cg * 8;
                #pragma unroll
                for (int sl = 0; sl < NS; ++sl)
                    aw[i][sl] = *(const bf16x8*)(op + (size_t)sl * 4194304);
            }
        }

        #pragma unroll
        for (int s = 0; s < 2; ++s) {
            const int sw = (s * 4 + quad);
            bf16x8 a[NI], b[4];
            #pragma unroll
            for (int i = 0; i < NI; ++i) {
                int row = wr + i * 16 + l16;
                a[i] = *(const bf16x8*)&As[(row * 8 + (sw ^ l8)) * 8];
            }
            #pragma unroll
            for (int j = 0; j < 4; ++j) {
                int row = wc + j * 16 + l16;
                b[j] = *(const bf16x8*)&Bs[(row * 8 + (sw ^ l8)) * 8];
            }
            #pragma unroll
            for (int i = 0; i < NI; ++i)
                #pragma unroll
                for (int j = 0; j < 4; ++j)
                    acc[i][j] = __builtin_amdgcn_mfma_f32_16x16x32_bf16(a[i], b[j], acc[i][j], 0, 0, 0);
        }
    }

    const float qscale = 0.18033688011112042f;   // 0.125 * log2(e)

    if (MODE == 0) {
        // ---- vectorized epilogue via swizzled LDS tile E[128][128] bf16 ----
        // swizzle: chunk' = (col>>3) ^ (row&15) ^ ((row>>3)&7), bijective/row.
        __syncthreads();                       // K-loop LDS reads complete
        bf16_t* E = smem;                      // 32 KB, reuses As+Bs
        const float qs = (n0 < 512) ? qscale : 1.0f;
        #pragma unroll
        for (int i = 0; i < NI; ++i) {
            #pragma unroll
            for (int j = 0; j < 4; ++j) {
                int col = wc + j * 16 + l16;
                float bv = bias[n0 + col];
                #pragma unroll
                for (int r = 0; r < 4; ++r) {
                    int row = wr + i * 16 + quad * 4 + r;
                    int sc = (((col >> 3) ^ (row & 15) ^ ((row >> 3) & 7)) << 3) + (col & 7);
                    E[row * 128 + sc] = (bf16_t)((acc[i][j][r] + bv) * qs);
                }
            }
        }
        __syncthreads();

        const int b_ = m0 >> 12;               // whole block within one batch
        if (n0 < 1024) {
            // Q/K: row-major dest [bh][n][64]; 8 lanes cover one 128B row
            bf16_t* dst = (n0 < 512) ? Qg : Kg;
            #pragma unroll
            for (int p = 0; p < 8; ++p) {
                int g = p * 256 + tid;                 // 0..2047 chunk id
                int c = g & 7, drow = g >> 3;          // drow 0..255
                int hsel = drow >> 7, nl = drow & 127;
                int col0 = hsel * 64 + c * 8;
                int sc = (((col0 >> 3) ^ (nl & 15) ^ ((nl >> 3) & 7)) << 3);
                bf16x8 v = *(const bf16x8*)&E[nl * 128 + sc];
                int hh = ((n0 + hsel * 64) >> 6) & 7;
                int n = (m0 & 4095) + nl;
                size_t idx = (((size_t)(b_ * 8 + hh) * 4096) + n) * 64 + c * 8;
                *(bf16x8*)(dst + idx) = v;
            }
        } else {
            // V: transposed dest Vt[bh][hd][4096]; column reads from E
            #pragma unroll
            for (int p = 0; p < 8; ++p) {
                int g = p * 256 + tid;                 // 0..2047 chunk id
                int cn8 = g & 15, hdrow = g >> 4;      // hdrow 0..127
                int hsel = hdrow >> 6, hd = hdrow & 63;
                int col = hsel * 64 + hd;
                bf16x8 v;
                #pragma unroll
                for (int k = 0; k < 8; ++k) {
                    int row = cn8 * 8 + k;
                    int sc = (((col >> 3) ^ (row & 15) ^ ((row >> 3) & 7)) << 3) + (col & 7);
                    v[k] = E[row * 128 + sc];
                }
                int hh = ((n0 + hsel * 64) >> 6) & 7;
                int nbase = (m0 & 4095) + cn8 * 8;
                size_t idx = ((size_t)(b_ * 8 + hh) * 64 + hd) * 4096 + nbase;
                *(bf16x8*)(Vtp + idx) = v;
            }
        }
    } else {
        #pragma unroll
        for (int i = 0; i < NI; ++i) {
            int mrow = m0 + wr + i * 16 + quad * 4;
            #pragma unroll
            for (int j = 0; j < 4; ++j) {
                int cgl = n0 + wc + j * 16 + l16;
                float bv = bias[cgl];
                #pragma unroll
                for (int r = 0; r < 4; ++r) {
                    int m = mrow + r;
                    Cout[(size_t)m * 512 + cgl] = acc[i][j][r] + bv;
                }
            }
        }
    }
}

// ---------------- flash attention, 256-row q-blocks + split-K ----------------
// Paired strips (st, 15-st): uniform 17 tiles/block, 512 blocks @ ns=4
// (register-capped at 2 blocks/CU; combined VGPR+AGPR ~208/thread - R17).
// kt loop split: FAST (kt < 4*st, branch-free, maskless; NO setprio - it
// fences compiler cross-s interleave) + TAIL (diag tiles, branchy mask path).
// MSHIFT folded into MFMA C-init (sv starts at -12). P in-register via
// cvt + permlane. o_part bf16. launch_bounds(256,2): tighter spills (R10).

__global__ __launch_bounds__(256, 2) void attn_ns2(
    const bf16_t* __restrict__ Qg, const bf16_t* __restrict__ Kg,
    const bf16_t* __restrict__ Vt,
    bf16_t* __restrict__ o_part, float* __restrict__ l_part, int nsplit)
{
    __shared__ bf16_t Ks[2][64][72];
    __shared__ bf16_t Vs[2][64][72];

    const int tid  = threadIdx.x;
    const int w    = tid >> 6, lane = tid & 63, l16 = lane & 15, quad = lane >> 4;
    const int bh   = blockIdx.x & 15, pr = (blockIdx.x >> 4) & 7, h = blockIdx.x >> 7;

    bf16_t* ob = o_part + (size_t)(h * 16 + bh) * 4096 * 64;
    float*  lb = l_part + (size_t)(h * 16 + bh) * 4096;

    const int srow = tid >> 3, scol = (tid & 7) * 8;
    const int srow1 = srow + 32;
    const float MSHIFT = 12.0f;

    bf16x8 ones;
    #pragma unroll
    for (int j = 0; j < 8; ++j) ones[j] = (bf16_t)1.0f;

    uint4 kr0, kr1, vr0, vr1;

// per-tile staging: write dbuf, barrier, prefetch next, load fragments
#define TILE_PROLOGUE()                                                        \
    const int cur = kt & 1;                                                    \
    *(uint4*)&Ks[cur][srow][scol]  = kr0;                                      \
    *(uint4*)&Ks[cur][srow1][scol] = kr1;                                      \
    *(uint4*)&Vs[cur][srow][scol]  = vr0;                                      \
    *(uint4*)&Vs[cur][srow1][scol] = vr1;                                      \
    __syncthreads();                                                           \
    if (kt + 1 < b1) {                                                         \
        const size_t kb = ((size_t)bh * 4096 + (kt + 1) * 64) * 64;            \
        const size_t vb = (size_t)bh * 64 * 4096 + (kt + 1) * 64;              \
        kr0 = *(const uint4*)(Kg + kb + (size_t)srow * 64 + scol);             \
        kr1 = *(const uint4*)(Kg + kb + (size_t)srow1 * 64 + scol);            \
        vr0 = *(const uint4*)(Vt + vb + (size_t)srow * 4096 + scol);           \
        vr1 = *(const uint4*)(Vt + vb + (size_t)srow1 * 4096 + scol);          \
    }                                                                          \
    bf16x8 kf[4][2], vf[4][2];                                                 \
    _Pragma("unroll")                                                          \
    for (int cb = 0; cb < 4; ++cb) {                                           \
        kf[cb][0] = *(const bf16x8*)&Ks[cur][cb * 16 + l16][quad * 8];         \
        kf[cb][1] = *(const bf16x8*)&Ks[cur][cb * 16 + l16][32 + quad * 8];    \
    }                                                                          \
    _Pragma("unroll")                                                          \
    for (int j = 0; j < 4; ++j) {                                              \
        vf[j][0] = *(const bf16x8*)&Vs[cur][j * 16 + l16][quad * 8];           \
        vf[j][1] = *(const bf16x8*)&Vs[cur][j * 16 + l16][32 + quad * 8];      \
    }

// softmax + permlane redistribution: sv[4] (f32x4, pre-shifted by -MSHIFT via
// C-init) -> pa0/pa1 bf16x8
#define SOFTMAX_PERMLANE(sv, pa0, pa1)                                         \
    unsigned int c_[4][2];                                                     \
    _Pragma("unroll")                                                          \
    for (int cb = 0; cb < 4; ++cb) {                                           \
        _Pragma("unroll")                                                      \
        for (int t = 0; t < 2; ++t) {                                          \
            bf16x2 pk2;                                                        \
            pk2[0] = (bf16_t)__builtin_amdgcn_exp2f(sv[cb][2 * t]);            \
            pk2[1] = (bf16_t)__builtin_amdgcn_exp2f(sv[cb][2 * t + 1]);        \
            c_[cb][t] = __builtin_bit_cast(unsigned int, pk2);                 \
        }                                                                      \
    }                                                                          \
    unsigned int pw0[4], pw1[4];                                               \
    _Pragma("unroll")                                                          \
    for (int t = 0; t < 2; ++t) {                                              \
        auto u  = __builtin_amdgcn_permlane32_swap(c_[0][t], c_[1][t], false, false); \
        auto z  = __builtin_amdgcn_permlane16_swap(u[0], u[1], false, false);  \
        pw0[t] = z[0]; pw0[t + 2] = z[1];                                      \
        auto u2 = __builtin_amdgcn_permlane32_swap(c_[2][t], c_[3][t], false, false); \
        auto z2 = __builtin_amdgcn_permlane16_swap(u2[0], u2[1], false, false); \
        pw1[t] = z2[0]; pw1[t + 2] = z2[1];                                    \
    }                                                                          \
    uint32x4 w0v = {pw0[0], pw0[1], pw0[2], pw0[3]};                           \
    uint32x4 w1v = {pw1[0], pw1[1], pw1[2], pw1[3]};                           \
    bf16x8 pa0 = __builtin_bit_cast(bf16x8, w0v);                              \
    bf16x8 pa1 = __builtin_bit_cast(bf16x8, w1v);

    for (int ph = 0; ph < 2; ++ph) {
        const int st = ph ? (15 - pr) : pr;          // 256-row strip index
        const int T  = 4 * st + 4;
        const int b0 = (h * T) / nsplit, b1 = ((h + 1) * T) / nsplit;
        const int st4 = 4 * st;
        const int fastEnd = (st4 < b1) ? st4 : b1;

        int qrow[4];
        bf16x8 qf[4][2];
        #pragma unroll
        for (int s = 0; s < 4; ++s) {
            qrow[s] = st * 256 + s * 64 + w * 16 + l16;
            const bf16_t* qp = Qg + ((size_t)bh * 4096 + qrow[s]) * 64;
            qf[s][0] = *(const bf16x8*)(qp + quad * 8);
            qf[s][1] = *(const bf16x8*)(qp + 32 + quad * 8);
        }

        f32x4 o[4][4] = {};
        f32x4 lacc[4] = {};

        {
            const size_t kb = ((size_t)bh * 4096 + b0 * 64) * 64;
            const size_t vb = (size_t)bh * 64 * 4096 + b0 * 64;
            kr0 = *(const uint4*)(Kg + kb + (size_t)srow * 64 + scol);
            kr1 = *(const uint4*)(Kg + kb + (size_t)srow1 * 64 + scol);
            vr0 = *(const uint4*)(Vt + vb + (size_t)srow * 4096 + scol);
            vr1 = *(const uint4*)(Vt + vb + (size_t)srow1 * 4096 + scol);
        }
        __syncthreads();

        int kt = b0;

        // ---- FAST path: full tiles, no masking, branch-free across s ----
        for (; kt < fastEnd; ++kt) {
            TILE_PROLOGUE();
            #pragma unroll
            for (int s = 0; s < 4; ++s) {
                f32x4 sv[4];
                #pragma unroll
                for (int cb = 0; cb < 4; ++cb)
                    sv[cb] = f32x4{-MSHIFT, -MSHIFT, -MSHIFT, -MSHIFT};
                #pragma unroll
                for (int cb = 0; cb < 4; ++cb) {
                    sv[cb] = __builtin_amdgcn_mfma_f32_16x16x32_bf16(kf[cb][0], qf[s][0], sv[cb], 0, 0, 0);
                    sv[cb] = __builtin_amdgcn_mfma_f32_16x16x32_bf16(kf[cb][1], qf[s][1], sv[cb], 0, 0, 0);
                }
                SOFTMAX_PERMLANE(sv, pa0, pa1);
                #pragma unroll
                for (int j = 0; j < 4; ++j) {
                    o[s][j] = __builtin_amdgcn_mfma_f32_16x16x32_bf16(pa0, vf[j][0], o[s][j], 0, 0, 0);
                    o[s][j] = __builtin_amdgcn_mfma_f32_16x16x32_bf16(pa1, vf[j][1], o[s][j], 0, 0, 0);
                }
                lacc[s] = __builtin_amdgcn_mfma_f32_16x16x32_bf16(pa0, ones, lacc[s], 0, 0, 0);
                lacc[s] = __builtin_amdgcn_mfma_f32_16x16x32_bf16(pa1, ones, lacc[s], 0, 0, 0);
            }
        }

        // ---- TAIL path: diagonal tiles (masking / partial s) ----
        for (; kt < b1; ++kt) {
            TILE_PROLOGUE();
            #pragma unroll
            for (int s = 0; s < 4; ++s) {
                const int diag = st4 + s;
                if (kt > diag) continue;

                f32x4 sv[4];
                #pragma unroll
                for (int cb = 0; cb < 4; ++cb)
                    sv[cb] = f32x4{-MSHIFT, -MSHIFT, -MSHIFT, -MSHIFT};
                #pragma unroll
                for (int cb = 0; cb < 4; ++cb) {
                    sv[cb] = __builtin_amdgcn_mfma_f32_16x16x32_bf16(kf[cb][0], qf[s][0], sv[cb], 0, 0, 0);
                    sv[cb] = __builtin_amdgcn_mfma_f32_16x16x32_bf16(kf[cb][1], qf[s][1], sv[cb], 0, 0, 0);
                }

                if (kt == diag) {
                    #pragma unroll
                    for (int cb = 0; cb < 4; ++cb) {
                        const int keyg = kt * 64 + cb * 16 + quad * 4;
                        #pragma unroll
                        for (int r = 0; r < 4; ++r)
                            if (keyg + r > qrow[s]) sv[cb][r] = -1e30f;
                    }
                }

                SOFTMAX_PERMLANE(sv, pa0, pa1);
                #pragma unroll
                for (int j = 0; j < 4; ++j) {
                    o[s][j] = __builtin_amdgcn_mfma_f32_16x16x32_bf16(pa0, vf[j][0], o[s][j], 0, 0, 0);
                    o[s][j] = __builtin_amdgcn_mfma_f32_16x16x32_bf16(pa1, vf[j][1], o[s][j], 0, 0, 0);
                }
                lacc[s] = __builtin_amdgcn_mfma_f32_16x16x32_bf16(pa0, ones, lacc[s], 0, 0, 0);
                lacc[s] = __builtin_amdgcn_mfma_f32_16x16x32_bf16(pa1, ones, lacc[s], 0, 0, 0);
            }
        }

        #pragma unroll
        for (int s = 0; s < 4; ++s)
            #pragma unroll
            for (int r = 0; r < 4; ++r) {
                int n = st * 256 + s * 64 + w * 16 + quad * 4 + r;
                #pragma unroll
                for (int j = 0; j < 4; ++j)
                    ob[(size_t)n * 64 + j * 16 + l16] = (bf16_t)o[s][j][r];
                if (l16 == 0) lb[n] = lacc[s][r];
            }
    }
#undef TILE_PROLOGUE
#undef SOFTMAX_PERMLANE
}

// ---------------- launch ----------------

extern "C" void kernel_launch(void* const* d_in, const int* in_sizes, int n_in,
                              void* d_out, int out_size, void* d_ws, size_t ws_size,
                              hipStream_t stream) {
    const float* x    = (const float*)d_in[0];   // [2,4096,512]
    const float* Wqkv = (const float*)d_in[1];   // [512,1536]
    const float* bqkv = (const float*)d_in[2];   // [1536]
    const float* Wout = (const float*)d_in[3];   // [512,512]
    const float* bout = (const float*)d_in[4];   // [512]
    float* out = (float*)d_out;                  // [2,4096,512] fp32

    char* ws = (char*)d_ws;
    bf16_t* xb  = (bf16_t*)(ws);                 // 8 MB
    bf16_t* WqT = (bf16_t*)(ws + 8388608);       // 1.5 MB
    bf16_t* WoT = (bf16_t*)(ws + 9961472);       // 0.5 MB
    bf16_t* Qg  = (bf16_t*)(ws + 10485760);      // 8 MB (pre-scaled)
    bf16_t* Kg  = (bf16_t*)(ws + 18874368);      // 8 MB
    bf16_t* Vt  = (bf16_t*)(ws + 27262976);      // 8 MB ([bh][64][4096], written
                                                 // directly by gemm<0> epilogue)

    // o_part bf16: slab = 16*4096*64*2B = 8388608; l_part fp32 after slabs.
    // ns=4 needs 35651584 + 4*8388608 + 4*262144 = 70254592 (fits).
    const int nsplit = 4;
    bf16_t* o_part = (bf16_t*)(ws + 35651584);
    float*  l_part = (float*)(ws + 35651584 + (size_t)nsplit * 8388608);

    prep_kernel<<<4352, 256, 0, stream>>>(x, xb, Wqkv, WqT, Wout, WoT);

    gemm_bt<0, 128><<<dim3(12, 64), 256, 0, stream>>>(
        xb, WqT, bqkv, Qg, Kg, Vt, nullptr, nullptr, nullptr);

    attn_ns2<<<128 * nsplit, 256, 0, stream>>>(Qg, Kg, Vt, o_part, l_part, nsplit);

    gemm_bt<1, 64><<<dim3(8, 64), 256, 0, stream>>>(
        nullptr, WoT, bout, nullptr, nullptr, nullptr, out, o_part, l_part);
}